// Round 1
// baseline (195.861 us; speedup 1.0000x reference)
//
#include <hip/hip_runtime.h>

typedef __attribute__((ext_vector_type(8))) short bf16x8;
typedef __attribute__((ext_vector_type(4))) float f32x4;

// ---------------------------------------------------------------------------
// f32 -> bf16 round-to-nearest-even
__device__ __forceinline__ unsigned short f2bf(float x) {
    unsigned u = __float_as_uint(x);
    u += 0x7fffu + ((u >> 16) & 1u);
    return (unsigned short)(u >> 16);
}

// Slice + convert + mask-zero rows.
// dst[(b*64 + i)*1024 + k] = (i < len[b]+lenAdj) ? bf16(src[b, i+1, k]) : 0
// Each thread handles 4 consecutive elements (float4 in, ushort4 out).
__global__ void conv_kernel(const float* __restrict__ src, const int* __restrict__ len,
                            unsigned short* __restrict__ dst, int rawL, int lenAdj)
{
    int idx = blockIdx.x * 256 + threadIdx.x;   // 8192*256 threads total
    int m = idx >> 8;                            // row 0..8191
    int c = (idx & 255) << 2;                    // col element 0..1020
    int b = m >> 6;
    int i = m & 63;
    int lim = len[b] + lenAdj;
    float4 v;
    if (i < lim) {
        v = *(const float4*)(src + ((size_t)(b * rawL + 1 + i) << 10) + c);
    } else {
        v = make_float4(0.f, 0.f, 0.f, 0.f);
    }
    ushort4 o;
    o.x = f2bf(v.x); o.y = f2bf(v.y); o.z = f2bf(v.z); o.w = f2bf(v.w);
    *(ushort4*)(dst + ((size_t)m << 10) + c) = o;
}

// ---------------------------------------------------------------------------
__device__ __forceinline__ void gload_lds16(const void* g, void* l) {
    __builtin_amdgcn_global_load_lds((const __attribute__((address_space(1))) void*)g,
                                     (__attribute__((address_space(3))) void*)l,
                                     16, 0, 0);
}

// m97-structure GEMM with fused per-(b,t)-block reduction.
// A: 8192x1024 bf16 (im rows), B: 8192x1024 bf16 (s rows), C = A*B^T.
// Tile 128x128, BK=64, 4 waves in 2x2; wave (wr,wc) owns one 64x64 (b,t) block.
// aggr[b*128+t] = sum_j max_i C_block[i][j]
__global__ void __launch_bounds__(256) gemm_aggr_kernel(const unsigned short* __restrict__ A,
                                                        const unsigned short* __restrict__ B,
                                                        float* __restrict__ aggr)
{
    __shared__ __align__(16) unsigned short As[128 * 64];
    __shared__ __align__(16) unsigned short Bs[128 * 64];

    const int tid  = threadIdx.x;
    const int lane = tid & 63;
    const int wid  = tid >> 6;
    const int wr   = wid >> 1;
    const int wc   = wid & 1;
    const int tm   = blockIdx.y;
    const int tn   = blockIdx.x;

    f32x4 acc[4][4];
#pragma unroll
    for (int mi = 0; mi < 4; ++mi)
#pragma unroll
        for (int ni = 0; ni < 4; ++ni)
            acc[mi][ni] = (f32x4){0.f, 0.f, 0.f, 0.f};

    const int srow = tid >> 3;          // 0..31 : row within 32-row staging slab
    const int scol = (tid & 7) << 3;    // element offset within 64-col K slab
    const size_t gA0 = ((size_t)(tm * 128) << 10);
    const size_t gB0 = ((size_t)(tn * 128) << 10);

    const int r15 = lane & 15;
    const int ko8 = (lane >> 4) << 3;

    for (int k0 = 0; k0 < 1024; k0 += 64) {
        __syncthreads();   // previous K-step's compute done before LDS overwrite
#pragma unroll
        for (int it = 0; it < 4; ++it) {
            const unsigned short* ga = A + gA0 + (((size_t)(it * 32 + srow)) << 10) + k0 + scol;
            gload_lds16(ga, (char*)As + it * 4096 + wid * 1024);
            const unsigned short* gb = B + gB0 + (((size_t)(it * 32 + srow)) << 10) + k0 + scol;
            gload_lds16(gb, (char*)Bs + it * 4096 + wid * 1024);
        }
        __syncthreads();   // vmcnt(0) drained before barrier -> tiles visible

#pragma unroll
        for (int kk = 0; kk < 2; ++kk) {
            const int ko = kk * 32 + ko8;
            bf16x8 af[4], bg[4];
#pragma unroll
            for (int mi = 0; mi < 4; ++mi)
                af[mi] = *(const bf16x8*)&As[(wr * 64 + mi * 16 + r15) * 64 + ko];
#pragma unroll
            for (int ni = 0; ni < 4; ++ni)
                bg[ni] = *(const bf16x8*)&Bs[(wc * 64 + ni * 16 + r15) * 64 + ko];
#pragma unroll
            for (int mi = 0; mi < 4; ++mi)
#pragma unroll
                for (int ni = 0; ni < 4; ++ni)
                    acc[mi][ni] = __builtin_amdgcn_mfma_f32_16x16x32_bf16(af[mi], bg[ni],
                                                                          acc[mi][ni], 0, 0, 0);
        }
    }

    // Fused reduction. C/D fragment layout: col = lane&15, row = (lane>>4)*4 + reg.
    // Per column j: max over all 64 rows, then sum over the block's 64 columns.
    float cm[4];
#pragma unroll
    for (int ni = 0; ni < 4; ++ni) {
        float m = acc[0][ni][0];
#pragma unroll
        for (int mi = 0; mi < 4; ++mi)
#pragma unroll
            for (int r = 0; r < 4; ++r)
                m = fmaxf(m, acc[mi][ni][r]);
        m = fmaxf(m, __shfl_xor(m, 16));
        m = fmaxf(m, __shfl_xor(m, 32));
        cm[ni] = m;   // column max for col = ni*16 + (lane&15), replicated over row-groups
    }
    float s = cm[0] + cm[1] + cm[2] + cm[3];
    s += __shfl_xor(s, 1);
    s += __shfl_xor(s, 2);
    s += __shfl_xor(s, 4);
    s += __shfl_xor(s, 8);
    if (lane == 0) {
        int b = tm * 2 + wr;
        int t = tn * 2 + wc;
        aggr[b * 128 + t] = s;
    }
}

// ---------------------------------------------------------------------------
// loss = sum_x max_{y!=x} relu(M + aggr[x,y] - aggr[x,x])
//      + sum_y max_{x!=y} relu(M + aggr[x,y] - aggr[y,y])
__global__ void loss_kernel(const float* __restrict__ aggr, float* __restrict__ out)
{
    __shared__ float red[128];
    const int x = threadIdx.x;
    const float diag = aggr[x * 128 + x];
    float mrow = 0.f, mcol = 0.f;
    for (int y = 0; y < 128; ++y) {
        if (y == x) continue;
        float a_xy = aggr[x * 128 + y];   // row x of aggr
        float a_yx = aggr[y * 128 + x];   // col x of aggr
        mrow = fmaxf(mrow, 0.2f + a_xy - diag);   // relu via 0-floor of running max
        mcol = fmaxf(mcol, 0.2f + a_yx - diag);
    }
    red[x] = mrow + mcol;
    __syncthreads();
    if (x == 0) {
        float s = 0.f;
        for (int i = 0; i < 128; ++i) s += red[i];
        *out = s;
    }
}

// ---------------------------------------------------------------------------
extern "C" void kernel_launch(void* const* d_in, const int* in_sizes, int n_in,
                              void* d_out, int out_size, void* d_ws, size_t ws_size,
                              hipStream_t stream)
{
    const float* im_set = (const float*)d_in[0];   // (128, 65, 1024) f32
    const float* s_seq  = (const float*)d_in[1];   // (128, 67, 1024) f32
    const int*   im_len = (const int*)d_in[2];     // (128,) i32
    const int*   s_len  = (const int*)d_in[3];     // (128,) i32
    float* out = (float*)d_out;

    unsigned short* Abf = (unsigned short*)d_ws;                           // 16 MiB
    unsigned short* Bbf = (unsigned short*)((char*)d_ws + (16u << 20));    // 16 MiB
    float*          agg = (float*)((char*)d_ws + (32u << 20));             // 64 KiB

    // Slice + mask + convert: im_set[:,1:,:] with rows >= im_len-1 zeroed,
    // s_seq[:,1:-2,:] with rows >= s_len-3 zeroed.
    conv_kernel<<<8192, 256, 0, stream>>>(im_set, im_len, Abf, 65, -1);
    conv_kernel<<<8192, 256, 0, stream>>>(s_seq,  s_len,  Bbf, 67, -3);

    gemm_aggr_kernel<<<dim3(64, 64), 256, 0, stream>>>(Abf, Bbf, agg);

    loss_kernel<<<1, 128, 0, stream>>>(agg, out);
}

// Round 2
// 181.682 us; speedup vs baseline: 1.0780x; 1.0780x over previous
//
#include <hip/hip_runtime.h>

typedef __attribute__((ext_vector_type(8))) short bf16x8;
typedef __attribute__((ext_vector_type(4))) float f32x4;

// ---------------------------------------------------------------------------
// f32 -> bf16 round-to-nearest-even
__device__ __forceinline__ unsigned short f2bf(float x) {
    unsigned u = __float_as_uint(x);
    u += 0x7fffu + ((u >> 16) & 1u);
    return (unsigned short)(u >> 16);
}

// Slice + convert + mask-zero rows.
__global__ void conv_kernel(const float* __restrict__ src, const int* __restrict__ len,
                            unsigned short* __restrict__ dst, int rawL, int lenAdj)
{
    int idx = blockIdx.x * 256 + threadIdx.x;
    int m = idx >> 8;
    int c = (idx & 255) << 2;
    int b = m >> 6;
    int i = m & 63;
    int lim = len[b] + lenAdj;
    float4 v;
    if (i < lim) {
        v = *(const float4*)(src + ((size_t)(b * rawL + 1 + i) << 10) + c);
    } else {
        v = make_float4(0.f, 0.f, 0.f, 0.f);
    }
    ushort4 o;
    o.x = f2bf(v.x); o.y = f2bf(v.y); o.z = f2bf(v.z); o.w = f2bf(v.w);
    *(ushort4*)(dst + ((size_t)m << 10) + c) = o;
}

// ---------------------------------------------------------------------------
__device__ __forceinline__ void gload_lds16(const void* g, void* l) {
    __builtin_amdgcn_global_load_lds((const __attribute__((address_space(1))) void*)g,
                                     (__attribute__((address_space(3))) void*)l,
                                     16, 0, 0);
}

// Phased GEMM, BM=256 BN=128 BK=64, 8 waves (4Mx2N), ring-3 LDS, counted vmcnt.
// Wave (wr,wc) owns one 64x64 (b,t) block -> fused max/sum reduction wave-local.
__global__ void __launch_bounds__(512) gemm_aggr_kernel(const unsigned short* __restrict__ A,
                                                        const unsigned short* __restrict__ B,
                                                        float* __restrict__ aggr)
{
    __shared__ __align__(16) unsigned short As[3][256 * 64];   // 3 x 32 KiB
    __shared__ __align__(16) unsigned short Bs[3][128 * 64];   // 3 x 16 KiB

    const int tid  = threadIdx.x;
    const int lane = tid & 63;
    const int wid  = tid >> 6;       // 0..7
    const int wr   = wid >> 1;       // 0..3  (64-row block within BM=256)
    const int wc   = wid & 1;        // 0..1  (64-col block within BN=128)
    const int tm   = blockIdx.y;     // 0..31
    const int tn   = blockIdx.x;     // 0..63

    const int r15 = lane & 15;
    const int g4  = lane >> 4;       // 0..3
    const int swz = r15 & 7;         // read-side XOR key (row mod 8)

    // Staging: each round = 64 rows x 64 cols, 512 thr x 16B. LDS dest linear;
    // global source chunk pre-swizzled so swizzled READ retrieves correct data.
    const int srow   = tid >> 3;                    // 0..63 row within round
    const int schunk = (tid & 7) ^ (srow & 7);      // pre-swizzled source chunk
    const unsigned short* gA_t = A + ((size_t)(tm * 256 + srow) << 10) + schunk * 8;
    const unsigned short* gB_t = B + ((size_t)(tn * 128 + srow) << 10) + schunk * 8;

#define STAGE_A(kt, ar) gload_lds16(gA_t + (((size_t)(ar) * 64) << 10) + (kt) * 64, \
                                    (char*)As[(kt) % 3] + (ar) * 8192 + wid * 1024)
#define STAGE_B(kt, br) gload_lds16(gB_t + (((size_t)(br) * 64) << 10) + (kt) * 64, \
                                    (char*)Bs[(kt) % 3] + (br) * 8192 + wid * 1024)

    f32x4 acc[4][4];
#pragma unroll
    for (int mi = 0; mi < 4; ++mi)
#pragma unroll
        for (int ni = 0; ni < 4; ++ni)
            acc[mi][ni] = (f32x4){0.f, 0.f, 0.f, 0.f};

    // Prologue: stage tiles 0 and 1 (6 loads each, tile-0 loads oldest).
#pragma unroll
    for (int pt = 0; pt < 2; ++pt) {
        STAGE_A(pt, 0); STAGE_A(pt, 1); STAGE_A(pt, 2); STAGE_A(pt, 3);
        STAGE_B(pt, 0); STAGE_B(pt, 1);
    }
    asm volatile("s_waitcnt vmcnt(6)" ::: "memory");   // tile 0 landed; tile 1 in flight
    __builtin_amdgcn_s_barrier();

    const int Aro = (wr * 64 + r15) * 128;   // byte row base within A slot
    const int Bro = (wc * 64 + r15) * 128;   // byte row base within B slot

    for (int kt = 0; kt < 16; ++kt) {
        const char* Aslot = (const char*)As[kt % 3];
        const char* Bslot = (const char*)Bs[kt % 3];

        // ---------------- phase 0 : kk = 0 ----------------
        bf16x8 af[4], bg[4];
        {
            const int ch = (g4 ^ swz) * 16;
#pragma unroll
            for (int mi = 0; mi < 4; ++mi)
                af[mi] = *(const bf16x8*)(Aslot + Aro + mi * 2048 + ch);
#pragma unroll
            for (int ni = 0; ni < 4; ++ni)
                bg[ni] = *(const bf16x8*)(Bslot + Bro + ni * 2048 + ch);
        }
        if (kt < 14) { STAGE_A(kt + 2, 0); STAGE_A(kt + 2, 1); STAGE_A(kt + 2, 2); }
        __builtin_amdgcn_s_barrier();
        asm volatile("s_waitcnt lgkmcnt(0)" ::: "memory");
        __builtin_amdgcn_sched_barrier(0);
        __builtin_amdgcn_s_setprio(1);
#pragma unroll
        for (int mi = 0; mi < 4; ++mi)
#pragma unroll
            for (int ni = 0; ni < 4; ++ni)
                acc[mi][ni] = __builtin_amdgcn_mfma_f32_16x16x32_bf16(af[mi], bg[ni],
                                                                      acc[mi][ni], 0, 0, 0);
        __builtin_amdgcn_s_setprio(0);
        __builtin_amdgcn_s_barrier();

        // ---------------- phase 1 : kk = 1 ----------------
        {
            const int ch = ((4 + g4) ^ swz) * 16;
#pragma unroll
            for (int mi = 0; mi < 4; ++mi)
                af[mi] = *(const bf16x8*)(Aslot + Aro + mi * 2048 + ch);
#pragma unroll
            for (int ni = 0; ni < 4; ++ni)
                bg[ni] = *(const bf16x8*)(Bslot + Bro + ni * 2048 + ch);
        }
        if (kt < 14) { STAGE_A(kt + 2, 3); STAGE_B(kt + 2, 0); STAGE_B(kt + 2, 1); }
        __builtin_amdgcn_s_barrier();
        asm volatile("s_waitcnt lgkmcnt(0)" ::: "memory");
        __builtin_amdgcn_sched_barrier(0);
        __builtin_amdgcn_s_setprio(1);
#pragma unroll
        for (int mi = 0; mi < 4; ++mi)
#pragma unroll
            for (int ni = 0; ni < 4; ++ni)
                acc[mi][ni] = __builtin_amdgcn_mfma_f32_16x16x32_bf16(af[mi], bg[ni],
                                                                      acc[mi][ni], 0, 0, 0);
        __builtin_amdgcn_s_setprio(0);
        // K-tile boundary: counted wait — tile kt+1 landed, tile kt+2 stays in flight.
        if (kt < 14)       { asm volatile("s_waitcnt vmcnt(6)" ::: "memory"); }
        else if (kt == 14) { asm volatile("s_waitcnt vmcnt(0)" ::: "memory"); }
        __builtin_amdgcn_s_barrier();
    }
#undef STAGE_A
#undef STAGE_B

    // Fused reduction. C/D layout: col = lane&15, row = (lane>>4)*4 + reg.
    float cm[4];
#pragma unroll
    for (int ni = 0; ni < 4; ++ni) {
        float m = acc[0][ni][0];
#pragma unroll
        for (int mi = 0; mi < 4; ++mi)
#pragma unroll
            for (int r = 0; r < 4; ++r)
                m = fmaxf(m, acc[mi][ni][r]);
        m = fmaxf(m, __shfl_xor(m, 16));
        m = fmaxf(m, __shfl_xor(m, 32));
        cm[ni] = m;
    }
    float s = cm[0] + cm[1] + cm[2] + cm[3];
    s += __shfl_xor(s, 1);
    s += __shfl_xor(s, 2);
    s += __shfl_xor(s, 4);
    s += __shfl_xor(s, 8);
    if (lane == 0) {
        int b = tm * 4 + wr;
        int t = tn * 2 + wc;
        aggr[b * 128 + t] = s;
    }
}

// ---------------------------------------------------------------------------
__global__ void loss_kernel(const float* __restrict__ aggr, float* __restrict__ out)
{
    __shared__ float red[128];
    const int x = threadIdx.x;
    const float diag = aggr[x * 128 + x];
    float mrow = 0.f, mcol = 0.f;
    for (int y = 0; y < 128; ++y) {
        if (y == x) continue;
        float a_xy = aggr[x * 128 + y];
        float a_yx = aggr[y * 128 + x];
        mrow = fmaxf(mrow, 0.2f + a_xy - diag);
        mcol = fmaxf(mcol, 0.2f + a_yx - diag);
    }
    red[x] = mrow + mcol;
    __syncthreads();
    if (x == 0) {
        float s = 0.f;
        for (int i = 0; i < 128; ++i) s += red[i];
        *out = s;
    }
}

// ---------------------------------------------------------------------------
extern "C" void kernel_launch(void* const* d_in, const int* in_sizes, int n_in,
                              void* d_out, int out_size, void* d_ws, size_t ws_size,
                              hipStream_t stream)
{
    const float* im_set = (const float*)d_in[0];
    const float* s_seq  = (const float*)d_in[1];
    const int*   im_len = (const int*)d_in[2];
    const int*   s_len  = (const int*)d_in[3];
    float* out = (float*)d_out;

    unsigned short* Abf = (unsigned short*)d_ws;                           // 16 MiB
    unsigned short* Bbf = (unsigned short*)((char*)d_ws + (16u << 20));    // 16 MiB
    float*          agg = (float*)((char*)d_ws + (32u << 20));             // 64 KiB

    conv_kernel<<<8192, 256, 0, stream>>>(im_set, im_len, Abf, 65, -1);
    conv_kernel<<<8192, 256, 0, stream>>>(s_seq,  s_len,  Bbf, 67, -3);

    gemm_aggr_kernel<<<dim3(64, 32), 512, 0, stream>>>(Abf, Bbf, agg);

    loss_kernel<<<1, 128, 0, stream>>>(agg, out);
}

// Round 3
// 148.650 us; speedup vs baseline: 1.3176x; 1.2222x over previous
//
#include <hip/hip_runtime.h>

typedef __attribute__((ext_vector_type(8))) short bf16x8;
typedef __attribute__((ext_vector_type(4))) float f32x4;

// ---------------------------------------------------------------------------
// f32 -> bf16 round-to-nearest-even
__device__ __forceinline__ unsigned short f2bf(float x) {
    unsigned u = __float_as_uint(x);
    u += 0x7fffu + ((u >> 16) & 1u);
    return (unsigned short)(u >> 16);
}

// Fused slice + convert + mask-zero for BOTH inputs (one launch).
// blocks 0..8191: im_set[:,1:,:]  rows >= im_len-1 zeroed -> Ad
// blocks 8192..16383: s_seq[:,1:-2,:] rows >= s_len-3 zeroed -> Bd
__global__ void conv_kernel(const float* __restrict__ im, const int* __restrict__ iml,
                            const float* __restrict__ ss, const int* __restrict__ sl,
                            unsigned short* __restrict__ Ad, unsigned short* __restrict__ Bd)
{
    int bid = blockIdx.x;
    const float* src; const int* len; unsigned short* dst; int rawL, adj;
    if (bid < 8192) { src = im; len = iml; dst = Ad; rawL = 65; adj = -1; }
    else { bid -= 8192; src = ss; len = sl; dst = Bd; rawL = 67; adj = -3; }
    int m = bid;                       // output row 0..8191
    int c = threadIdx.x << 2;          // col element
    int b = m >> 6;
    int i = m & 63;
    int lim = len[b] + adj;
    float4 v;
    if (i < lim) {
        v = *(const float4*)(src + ((size_t)(b * rawL + 1 + i) << 10) + c);
    } else {
        v = make_float4(0.f, 0.f, 0.f, 0.f);
    }
    ushort4 o;
    o.x = f2bf(v.x); o.y = f2bf(v.y); o.z = f2bf(v.z); o.w = f2bf(v.w);
    *(ushort4*)(dst + ((size_t)m << 10) + c) = o;
}

// ---------------------------------------------------------------------------
__device__ __forceinline__ void gload_lds16(const void* g, void* l) {
    __builtin_amdgcn_global_load_lds((const __attribute__((address_space(1))) void*)g,
                                     (__attribute__((address_space(3))) void*)l,
                                     16, 0, 0);
}

// 256x256 tile GEMM, BK=64, 8 waves (2M x 4N), per-wave 128x64 output.
// 4 phases/K-tile (one 32-row C-quadrant each), B-frags hoisted per tile.
// Need-gated counted vmcnt: staging order per tile {B01,B23,A02,A13};
// gates: ph0 vmcnt(2), ph2 vmcnt(4). Barriers only at ph0/ph2.
// Wave-local fused reduction: aggr[b,t] = sum_j max_i C_block.
__global__ void __launch_bounds__(512) gemm_aggr_kernel(const unsigned short* __restrict__ A,
                                                        const unsigned short* __restrict__ B,
                                                        float* __restrict__ aggr)
{
    __shared__ __align__(16) unsigned short As[2][256 * 64];   // 2 x 32 KiB
    __shared__ __align__(16) unsigned short Bs[2][256 * 64];   // 2 x 32 KiB

    const int tid  = threadIdx.x;
    const int lane = tid & 63;
    const int wid  = tid >> 6;        // 0..7
    const int wr   = wid >> 2;        // 0..1 : 128-row half of BM
    const int wc   = wid & 3;         // 0..3 : 64-col quarter of BN
    const int tm   = blockIdx.y;      // 0..31
    const int tn   = blockIdx.x;      // 0..31

    const int r15 = lane & 15;
    const int g4  = lane >> 4;        // 0..3
    const int swz = r15 & 7;          // read-side XOR key (row mod 8)

    // Staging: each round = 64 rows x 64 cols (8 KB), 512 thr x 16 B.
    // LDS dest linear; global source chunk pre-swizzled (both-sides XOR).
    const int srow   = tid >> 3;                  // 0..63
    const int schunk = (tid & 7) ^ (srow & 7);
    const unsigned short* gA_t = A + ((size_t)(tm * 256 + srow) << 10) + schunk * 8;
    const unsigned short* gB_t = B + ((size_t)(tn * 256 + srow) << 10) + schunk * 8;

#define STAGE_A(kt, r) gload_lds16(gA_t + (((size_t)((r) * 64)) << 10) + (kt) * 64, \
                                   (char*)As[(kt) & 1] + (r) * 8192 + tid * 16)
#define STAGE_B(kt, r) gload_lds16(gB_t + (((size_t)((r) * 64)) << 10) + (kt) * 64, \
                                   (char*)Bs[(kt) & 1] + (r) * 8192 + tid * 16)

    f32x4 acc[4][2][4];   // [quadrant p][mi][ni]
#pragma unroll
    for (int p = 0; p < 4; ++p)
#pragma unroll
        for (int mi = 0; mi < 2; ++mi)
#pragma unroll
            for (int ni = 0; ni < 4; ++ni)
                acc[p][mi][ni] = (f32x4){0.f, 0.f, 0.f, 0.f};

    // Prologue: tile 0 in steady-state order [B0 B1 B2 B3 A0 A2 A1 A3].
    STAGE_B(0, 0); STAGE_B(0, 1); STAGE_B(0, 2); STAGE_B(0, 3);
    STAGE_A(0, 0); STAGE_A(0, 2); STAGE_A(0, 1); STAGE_A(0, 3);

    const int Bro = (wc * 64 + r15) * 128;       // B row byte base in slot
    const int ch0 = (g4 ^ swz) * 16;             // kk=0 chunk byte
    const int ch1 = ((4 + g4) ^ swz) * 16;       // kk=1 chunk byte

#pragma unroll 2
    for (int kt = 0; kt < 16; ++kt) {
        const char* Ab = (const char*)As[kt & 1];
        const char* Bb = (const char*)Bs[kt & 1];
        bf16x8 bg[4][2];

#pragma unroll
        for (int p = 0; p < 4; ++p) {
            if (p == 0) {
                // need: B rounds 0-3 + A rounds 0,2 of this tile (6 oldest)
                asm volatile("s_waitcnt vmcnt(2)" ::: "memory");
                __builtin_amdgcn_s_barrier();
                __builtin_amdgcn_sched_barrier(0);
#pragma unroll
                for (int ni = 0; ni < 4; ++ni) {
                    bg[ni][0] = *(const bf16x8*)(Bb + Bro + ni * 2048 + ch0);
                    bg[ni][1] = *(const bf16x8*)(Bb + Bro + ni * 2048 + ch1);
                }
            }
            if (p == 2) {
                // need: A rounds 1,3 of this tile
                if (kt < 15) { asm volatile("s_waitcnt vmcnt(4)" ::: "memory"); }
                else         { asm volatile("s_waitcnt vmcnt(0)" ::: "memory"); }
                __builtin_amdgcn_s_barrier();
                __builtin_amdgcn_sched_barrier(0);
            }

            // A-frags for this 32-row quadrant
            bf16x8 af[2][2];
            const int Aro = (wr * 128 + p * 32 + r15) * 128;
#pragma unroll
            for (int mi = 0; mi < 2; ++mi) {
                af[mi][0] = *(const bf16x8*)(Ab + Aro + mi * 2048 + ch0);
                af[mi][1] = *(const bf16x8*)(Ab + Aro + mi * 2048 + ch1);
            }

            // stage next tile (order: B01 | B23 | A02 | A13)
            if (kt < 15) {
                if (p == 0) { STAGE_B(kt + 1, 0); STAGE_B(kt + 1, 1); }
                if (p == 1) { STAGE_B(kt + 1, 2); STAGE_B(kt + 1, 3); }
                if (p == 2) { STAGE_A(kt + 1, 0); STAGE_A(kt + 1, 2); }
                if (p == 3) { STAGE_A(kt + 1, 1); STAGE_A(kt + 1, 3); }
            }

            asm volatile("s_waitcnt lgkmcnt(0)" ::: "memory");
            __builtin_amdgcn_sched_barrier(0);
            __builtin_amdgcn_s_setprio(1);
#pragma unroll
            for (int mi = 0; mi < 2; ++mi)
#pragma unroll
                for (int ni = 0; ni < 4; ++ni) {
                    acc[p][mi][ni] = __builtin_amdgcn_mfma_f32_16x16x32_bf16(af[mi][0], bg[ni][0],
                                                                             acc[p][mi][ni], 0, 0, 0);
                    acc[p][mi][ni] = __builtin_amdgcn_mfma_f32_16x16x32_bf16(af[mi][1], bg[ni][1],
                                                                             acc[p][mi][ni], 0, 0, 0);
                }
            __builtin_amdgcn_s_setprio(0);
        }
    }
#undef STAGE_A
#undef STAGE_B

    // Fused reduction per 64x64 (b,t) cell. C/D: col=lane&15, row=(lane>>4)*4+reg.
    // Wave covers 2 cells: h=0 -> quadrants 0,1 ; h=1 -> quadrants 2,3.
#pragma unroll
    for (int h = 0; h < 2; ++h) {
        float cm[4];
#pragma unroll
        for (int ni = 0; ni < 4; ++ni) {
            float m = acc[h * 2][0][ni][0];
#pragma unroll
            for (int pp = 0; pp < 2; ++pp)
#pragma unroll
                for (int mi = 0; mi < 2; ++mi)
#pragma unroll
                    for (int r = 0; r < 4; ++r)
                        m = fmaxf(m, acc[h * 2 + pp][mi][ni][r]);
            m = fmaxf(m, __shfl_xor(m, 16));
            m = fmaxf(m, __shfl_xor(m, 32));
            cm[ni] = m;
        }
        float s = cm[0] + cm[1] + cm[2] + cm[3];
        s += __shfl_xor(s, 1);
        s += __shfl_xor(s, 2);
        s += __shfl_xor(s, 4);
        s += __shfl_xor(s, 8);
        if (lane == 0) {
            int b = tm * 4 + wr * 2 + h;
            int t = tn * 4 + wc;
            aggr[b * 128 + t] = s;
        }
    }
}

// ---------------------------------------------------------------------------
__global__ void loss_kernel(const float* __restrict__ aggr, float* __restrict__ out)
{
    __shared__ float red[128];
    const int x = threadIdx.x;
    const float diag = aggr[x * 128 + x];
    float mrow = 0.f, mcol = 0.f;
    for (int y = 0; y < 128; ++y) {
        if (y == x) continue;
        float a_xy = aggr[x * 128 + y];
        float a_yx = aggr[y * 128 + x];
        mrow = fmaxf(mrow, 0.2f + a_xy - diag);
        mcol = fmaxf(mcol, 0.2f + a_yx - diag);
    }
    red[x] = mrow + mcol;
    __syncthreads();
    if (x == 0) {
        float s = 0.f;
        for (int i = 0; i < 128; ++i) s += red[i];
        *out = s;
    }
}

// ---------------------------------------------------------------------------
extern "C" void kernel_launch(void* const* d_in, const int* in_sizes, int n_in,
                              void* d_out, int out_size, void* d_ws, size_t ws_size,
                              hipStream_t stream)
{
    const float* im_set = (const float*)d_in[0];
    const float* s_seq  = (const float*)d_in[1];
    const int*   im_len = (const int*)d_in[2];
    const int*   s_len  = (const int*)d_in[3];
    float* out = (float*)d_out;

    unsigned short* Abf = (unsigned short*)d_ws;                           // 16 MiB
    unsigned short* Bbf = (unsigned short*)((char*)d_ws + (16u << 20));    // 16 MiB
    float*          agg = (float*)((char*)d_ws + (32u << 20));             // 64 KiB

    conv_kernel<<<16384, 256, 0, stream>>>(im_set, im_len, s_seq, s_len, Abf, Bbf);

    gemm_aggr_kernel<<<dim3(32, 32), 512, 0, stream>>>(Abf, Bbf, agg);

    loss_kernel<<<1, 128, 0, stream>>>(agg, out);
}